// Round 8
// baseline (179.968 us; speedup 1.0000x reference)
//
#include <hip/hip_runtime.h>
#include <cstdint>

#define N_SEQ 8
#define B_DIM 64
#define H_DIM 128
#define F_DIM 256
#define HS 64

typedef __attribute__((ext_vector_type(8))) short short8;
typedef __attribute__((ext_vector_type(4))) float floatx4;

__device__ __forceinline__ ushort f2bf(float f) {
    union { float f; uint32_t u; } v; v.f = f;
    uint32_t r = v.u + 0x7FFF + ((v.u >> 16) & 1);   // RNE
    return (ushort)(r >> 16);
}

// async 16B-per-lane global -> LDS (wave-uniform LDS base + lane*16)
__device__ __forceinline__ void async_ld16(const ushort* g, ushort* lds) {
    __builtin_amdgcn_global_load_lds(
        (const __attribute__((address_space(1))) unsigned int*)g,
        (__attribute__((address_space(3))) unsigned int*)lds,
        16, 0, 0);
}

// ---------------- W transpose + cast: Wtb[n=192][k=256] bf16 ----------------
__global__ __launch_bounds__(256) void prep_w(
    const float* __restrict__ Wq, const float* __restrict__ Wk,
    const float* __restrict__ Wv, ushort* __restrict__ Wtb)
{
    const int n = blockIdx.x;                 // 0..191
    const float* W = (n < 64) ? Wq : (n < 128) ? Wk : Wv;
    const int c = n & 63;
    const int k = threadIdx.x;                // 0..255
    Wtb[n * 256 + k] = f2bf(W[k * 64 + c]);
}

// ---------------- QKV projection: LDS-free, barrier-free MFMA GEMM --------
// 1024 blocks x 4 waves; wave owns 16 rows x all 192 n (two passes of 6
// n-tiles). A-frags direct from x (fp32->bf16 in regs); B-frags from
// L2-hot Wtb with one-ks-ahead prefetch. No LDS, no __syncthreads.
__global__ __launch_bounds__(256, 4) void proj_mfma(
    const float* __restrict__ x, const ushort* __restrict__ Wtb,
    ushort* __restrict__ Qb, ushort* __restrict__ Kb, ushort* __restrict__ Vtb)
{
    const int t = threadIdx.x;
    const int w = t >> 6, lane = t & 63;
    const int q16 = lane >> 4, l16 = lane & 15;
    const int64_t row0w = (int64_t)blockIdx.x * 64 + w * 16;

    const float* __restrict__ xrow = x + (row0w + l16) * F_DIM;
    const float qscale = 0.0625f * 1.44269504f;

    #pragma unroll 1
    for (int pass = 0; pass < 2; ++pass) {
        const int nbase = pass * 96;

        floatx4 acc[6];
        #pragma unroll
        for (int nt = 0; nt < 6; ++nt) acc[nt] = (floatx4){0.f, 0.f, 0.f, 0.f};

        short8 b0[6], b1[6];
        #pragma unroll
        for (int nt = 0; nt < 6; ++nt)
            b0[nt] = *(const short8*)&Wtb[(nbase + nt * 16 + l16) * 256 + q16 * 8];
        float4 a0 = *(const float4*)&xrow[q16 * 8];
        float4 a1 = *(const float4*)&xrow[q16 * 8 + 4];

        #pragma unroll
        for (int ks = 0; ks < 8; ++ks) {
            const float4 ca0 = a0, ca1 = a1;
            short8* cur = (ks & 1) ? b1 : b0;
            short8* nxt = (ks & 1) ? b0 : b1;
            if (ks < 7) {
                a0 = *(const float4*)&xrow[(ks + 1) * 32 + q16 * 8];
                a1 = *(const float4*)&xrow[(ks + 1) * 32 + q16 * 8 + 4];
                #pragma unroll
                for (int nt = 0; nt < 6; ++nt)
                    nxt[nt] = *(const short8*)&Wtb[(nbase + nt * 16 + l16) * 256 + (ks + 1) * 32 + q16 * 8];
            }
            union { short8 s; ushort u[8]; } af;
            af.u[0] = f2bf(ca0.x); af.u[1] = f2bf(ca0.y);
            af.u[2] = f2bf(ca0.z); af.u[3] = f2bf(ca0.w);
            af.u[4] = f2bf(ca1.x); af.u[5] = f2bf(ca1.y);
            af.u[6] = f2bf(ca1.z); af.u[7] = f2bf(ca1.w);
            #pragma unroll
            for (int nt = 0; nt < 6; ++nt)
                acc[nt] = __builtin_amdgcn_mfma_f32_16x16x32_bf16(af.s, cur[nt], acc[nt], 0, 0, 0);
        }

        // epilogue: C row = q16*4+r (m), col = l16 (n within tile)
        const int64_t g = row0w + q16 * 4;
        #pragma unroll
        for (int nt = 0; nt < 6; ++nt) {
            const int nb = nbase + nt * 16;          // wave-uniform
            const int n = nb + l16;
            if (nb < 64) {
                #pragma unroll
                for (int r = 0; r < 4; ++r)
                    Qb[(g + r) * 64 + n] = f2bf(acc[nt][r] * qscale);
            } else if (nb < 128) {
                #pragma unroll
                for (int r = 0; r < 4; ++r)
                    Kb[(g + r) * 64 + (n - 64)] = f2bf(acc[nt][r]);
            } else {
                const int d = n - 128;
                const int ib = (int)(g >> 7);
                const int h = (int)(g & 127);
                *(ushort4*)&Vtb[((int64_t)(ib * 64 + d)) * 128 + h] =
                    make_ushort4(f2bf(acc[nt][0]), f2bf(acc[nt][1]),
                                 f2bf(acc[nt][2]), f2bf(acc[nt][3]));
            }
        }
    }
}

// ---------------- attention: async dbuf + unnormalized-P chunk pipeline ----
// 512 blocks (one per jb, 2/CU). Frag-linear LDS tiles. Wave w: p-halves
// {w*16+l16, 64+w*16+l16}. Per kq-chunk: S-MFMA -> exp2 -> bf16 P (unnorm)
// -> LDS -> PV-MFMA into pv; of += rcp(l)*pv at iter end.
#define PT_STRIDE 40    // 32 + 8 pad (80 B rows, 16B-aligned b128 reads)
__global__ __launch_bounds__(256, 2) void attn_mfma(
    const ushort* __restrict__ Qb, const ushort* __restrict__ Kb,
    const ushort* __restrict__ Vtb, float* __restrict__ out)
{
    __shared__ ushort Ks[2][8192];            // 2 x 16 KB, frag-linear
    __shared__ ushort Vt[2][8192];            // 2 x 16 KB, frag-linear
    __shared__ ushort Ps[4][2][16 * PT_STRIDE];  // 10,240 B

    const int t = threadIdx.x;
    const int blk = blockIdx.x;
    const int b  = ((blk & 7) << 3) | ((blk >> 3) & 7);   // XCD-major b
    const int j  = blk >> 6;
    const int jb = j * 64 + b;

    const int w = t >> 6, lane = t & 63;
    const int q16 = lane >> 4, l16 = lane & 15;

    // staging frag assignment: fi = w*4+u
    int koff[4], voff[4], ldsoff[4];
    #pragma unroll
    for (int u = 0; u < 4; ++u) {
        const int fi = w * 4 + u;
        koff[u] = ((fi & 7) * 16 + l16) * 64 + (fi >> 3) * 32 + q16 * 8;
        voff[u] = ((fi & 3) * 16 + l16) * 128 + (fi >> 2) * 32 + q16 * 8;
        ldsoff[u] = fi * 512;   // ushorts
    }

    // Q B-frags for both halves (Qb pre-scaled by log2e/16)
    const int prow = jb * H_DIM + w * 16 + l16;
    short8 qa[2][2];
    #pragma unroll
    for (int hh = 0; hh < 2; ++hh)
        #pragma unroll
        for (int ks = 0; ks < 2; ++ks)
            qa[hh][ks] = *(const short8*)&Qb[(prow + hh * 64) * 64 + ks * 32 + q16 * 8];

    floatx4 of[2][4];
    #pragma unroll
    for (int hh = 0; hh < 2; ++hh)
        #pragma unroll
        for (int mt = 0; mt < 4; ++mt) of[hh][mt] = (floatx4){0.f, 0.f, 0.f, 0.f};

    // ---- prologue: stage tile 0 into buffer 0 ----
    {
        const ushort* kg = Kb + ((int64_t)b << 13);
        const ushort* vg = Vtb + ((int64_t)b << 13);
        #pragma unroll
        for (int u = 0; u < 4; ++u) {
            const int lo = __builtin_amdgcn_readfirstlane(ldsoff[u]);
            async_ld16(kg + koff[u], &Ks[0][lo]);
            async_ld16(vg + voff[u], &Vt[0][lo]);
        }
    }

    for (int i = 0; i < N_SEQ; ++i) {
        const int buf = i & 1;
        __syncthreads();   // drains stage(i); protects buf^1's prior readers

        if (i < N_SEQ - 1) {   // async stage of tile i+1
            const ushort* kg = Kb + ((int64_t)((i + 1) * B_DIM + b) << 13);
            const ushort* vg = Vtb + ((int64_t)((i + 1) * B_DIM + b) << 13);
            #pragma unroll
            for (int u = 0; u < 4; ++u) {
                const int lo = __builtin_amdgcn_readfirstlane(ldsoff[u]);
                async_ld16(kg + koff[u], &Ks[buf ^ 1][lo]);
                async_ld16(vg + voff[u], &Vt[buf ^ 1][lo]);
            }
        }

        float l[2] = {0.f, 0.f};
        floatx4 pv[2][4];
        #pragma unroll
        for (int hh = 0; hh < 2; ++hh)
            #pragma unroll
            for (int mt = 0; mt < 4; ++mt) pv[hh][mt] = (floatx4){0.f, 0.f, 0.f, 0.f};

        #pragma unroll
        for (int kq = 0; kq < 4; ++kq) {
            // ---- S^T chunk (q-tiles kq*2, kq*2+1) for both halves ----
            floatx4 sc[2][2];
            #pragma unroll
            for (int hh = 0; hh < 2; ++hh)
                #pragma unroll
                for (int tt = 0; tt < 2; ++tt) sc[hh][tt] = (floatx4){0.f, 0.f, 0.f, 0.f};
            #pragma unroll
            for (int ks = 0; ks < 2; ++ks)
                #pragma unroll
                for (int tt = 0; tt < 2; ++tt) {
                    const short8 ak = *(const short8*)&Ks[buf][(ks * 8 + kq * 2 + tt) * 512 + lane * 8];
                    sc[0][tt] = __builtin_amdgcn_mfma_f32_16x16x32_bf16(ak, qa[0][ks], sc[0][tt], 0, 0, 0);
                    sc[1][tt] = __builtin_amdgcn_mfma_f32_16x16x32_bf16(ak, qa[1][ks], sc[1][tt], 0, 0, 0);
                }

            // ---- exp2 (unnormalized), side-accumulate l, write P chunk ----
            #pragma unroll
            for (int hh = 0; hh < 2; ++hh)
                #pragma unroll
                for (int tt = 0; tt < 2; ++tt) {
                    const float e0 = __builtin_amdgcn_exp2f(sc[hh][tt][0]);
                    const float e1 = __builtin_amdgcn_exp2f(sc[hh][tt][1]);
                    const float e2 = __builtin_amdgcn_exp2f(sc[hh][tt][2]);
                    const float e3 = __builtin_amdgcn_exp2f(sc[hh][tt][3]);
                    l[hh] += (e0 + e1) + (e2 + e3);
                    *(ushort4*)&Ps[w][hh][l16 * PT_STRIDE + tt * 16 + q16 * 4] =
                        make_ushort4(f2bf(e0), f2bf(e1), f2bf(e2), f2bf(e3));
                }

            // ---- PV chunk into pv (unnormalized) ----
            const short8 bp0 = *(const short8*)&Ps[w][0][l16 * PT_STRIDE + q16 * 8];
            const short8 bp1 = *(const short8*)&Ps[w][1][l16 * PT_STRIDE + q16 * 8];
            #pragma unroll
            for (int mt = 0; mt < 4; ++mt) {
                const short8 av = *(const short8*)&Vt[buf][(kq * 4 + mt) * 512 + lane * 8];
                pv[0][mt] = __builtin_amdgcn_mfma_f32_16x16x32_bf16(av, bp0, pv[0][mt], 0, 0, 0);
                pv[1][mt] = __builtin_amdgcn_mfma_f32_16x16x32_bf16(av, bp1, pv[1][mt], 0, 0, 0);
            }
        }

        // ---- normalize this i's contribution: of += (1/l) * pv ----
        #pragma unroll
        for (int hh = 0; hh < 2; ++hh) {
            float lt = l[hh];
            lt += __shfl_xor(lt, 16);
            lt += __shfl_xor(lt, 32);
            const float inv = __builtin_amdgcn_rcpf(lt);
            #pragma unroll
            for (int mt = 0; mt < 4; ++mt)
                #pragma unroll
                for (int r = 0; r < 4; ++r)
                    of[hh][mt][r] = fmaf(inv, pv[hh][mt][r], of[hh][mt][r]);
        }
    }

    // ---- epilogue: O^T C-layout -> float4 stores (4 consecutive d) ----
    #pragma unroll
    for (int hh = 0; hh < 2; ++hh)
        #pragma unroll
        for (int mt = 0; mt < 4; ++mt)
            *(float4*)&out[(int64_t)(prow + hh * 64) * HS + mt * 16 + q16 * 4] =
                make_float4(of[hh][mt][0], of[hh][mt][1], of[hh][mt][2], of[hh][mt][3]);
}

extern "C" void kernel_launch(void* const* d_in, const int* in_sizes, int n_in,
                              void* d_out, int out_size, void* d_ws, size_t ws_size,
                              hipStream_t stream)
{
    const float* x  = (const float*)d_in[0];
    const float* Wq = (const float*)d_in[1];
    const float* Wk = (const float*)d_in[2];
    const float* Wv = (const float*)d_in[3];
    float* out = (float*)d_out;

    const size_t qkv = (size_t)N_SEQ * B_DIM * H_DIM * HS;   // 4,194,304 elems
    ushort* Qb  = (ushort*)d_ws;
    ushort* Kb  = Qb + qkv;
    ushort* Vtb = Kb + qkv;
    ushort* Wtb = Vtb + qkv;                                 // 192*256 elems

    prep_w<<<192, 256, 0, stream>>>(Wq, Wk, Wv, Wtb);
    proj_mfma<<<(N_SEQ * B_DIM * H_DIM) / 64, 256, 0, stream>>>(x, Wtb, Qb, Kb, Vtb);
    attn_mfma<<<N_SEQ * B_DIM, 256, 0, stream>>>(Qb, Kb, Vtb, out);
}

// Round 9
// 149.502 us; speedup vs baseline: 1.2038x; 1.2038x over previous
//
#include <hip/hip_runtime.h>
#include <cstdint>

#define N_SEQ 8
#define B_DIM 64
#define H_DIM 128
#define F_DIM 256
#define HS 64

typedef __attribute__((ext_vector_type(8))) short short8;
typedef __attribute__((ext_vector_type(4))) float floatx4;

__device__ __forceinline__ ushort f2bf(float f) {
    union { float f; uint32_t u; } v; v.f = f;
    uint32_t r = v.u + 0x7FFF + ((v.u >> 16) & 1);   // RNE
    return (ushort)(r >> 16);
}

// async 16B-per-lane global -> LDS (wave-uniform LDS base + lane*16)
__device__ __forceinline__ void async_ld16(const ushort* g, ushort* lds) {
    __builtin_amdgcn_global_load_lds(
        (const __attribute__((address_space(1))) unsigned int*)g,
        (__attribute__((address_space(3))) unsigned int*)lds,
        16, 0, 0);
}

// ---------------- W transpose + cast: Wtb[n=192][k=256] bf16 ----------------
__global__ __launch_bounds__(256) void prep_w(
    const float* __restrict__ Wq, const float* __restrict__ Wk,
    const float* __restrict__ Wv, ushort* __restrict__ Wtb)
{
    const int n = blockIdx.x;                 // 0..191
    const float* W = (n < 64) ? Wq : (n < 128) ? Wk : Wv;
    const int c = n & 63;
    const int k = threadIdx.x;                // 0..255
    Wtb[n * 256 + k] = f2bf(W[k * 64 + c]);
}

// ---------------- QKV projection via MFMA (R4 structure + 3-deep B pipe) --
// 1024 blocks x 64 rows. 4 waves; wave w owns n-slice [w*48, w*48+48).
// Qb pre-scaled by log2(e)/16 (folds softmax scale + exp2 conversion).
#define XS_STRIDE 264   // 256 + 8 pad (bf16 elems)
__global__ __launch_bounds__(256, 4) void proj_mfma(
    const float* __restrict__ x, const ushort* __restrict__ Wtb,
    ushort* __restrict__ Qb, ushort* __restrict__ Kb, ushort* __restrict__ Vtb)
{
    __shared__ ushort xs[64 * XS_STRIDE];     // 33,792 B
    const int t = threadIdx.x;
    const int blk = blockIdx.x;
    const int64_t row0 = (int64_t)blk * 64;

    const float4* xg = (const float4*)(x + row0 * F_DIM);
    #pragma unroll
    for (int u = 0; u < 8; ++u) {
        const int idx = t + 256 * u;
        const int row = idx >> 5;
        const int c8 = (idx & 31) * 8;
        const float4 a = xg[idx * 2];
        const float4 b = xg[idx * 2 + 1];
        *(ushort4*)&xs[row * XS_STRIDE + c8] =
            make_ushort4(f2bf(a.x), f2bf(a.y), f2bf(a.z), f2bf(a.w));
        *(ushort4*)&xs[row * XS_STRIDE + c8 + 4] =
            make_ushort4(f2bf(b.x), f2bf(b.y), f2bf(b.z), f2bf(b.w));
    }
    __syncthreads();

    const int w = t >> 6, lane = t & 63;
    const int q16 = lane >> 4, l16 = lane & 15;
    const int n0 = w * 48;

    floatx4 acc[4][3];
    #pragma unroll
    for (int mt = 0; mt < 4; ++mt)
        #pragma unroll
        for (int nt = 0; nt < 3; ++nt) acc[mt][nt] = (floatx4){0.f, 0.f, 0.f, 0.f};

    // 3-stage rolling B prefetch (covers L2 latency ~2-3 iterations)
    short8 bq[3][3];
    #pragma unroll
    for (int s = 0; s < 3; ++s)
        #pragma unroll
        for (int nt = 0; nt < 3; ++nt)
            bq[s][nt] = *(const short8*)&Wtb[(n0 + nt * 16 + l16) * 256 + s * 32 + q16 * 8];

    #pragma unroll
    for (int ks = 0; ks < 8; ++ks) {
        short8 cur[3];
        #pragma unroll
        for (int nt = 0; nt < 3; ++nt) cur[nt] = bq[ks % 3][nt];
        if (ks < 5) {
            #pragma unroll
            for (int nt = 0; nt < 3; ++nt)
                bq[ks % 3][nt] = *(const short8*)&Wtb[(n0 + nt * 16 + l16) * 256 + (ks + 3) * 32 + q16 * 8];
        }
        #pragma unroll
        for (int mt = 0; mt < 4; ++mt) {
            const short8 afr = *(const short8*)&xs[(mt * 16 + l16) * XS_STRIDE + ks * 32 + q16 * 8];
            #pragma unroll
            for (int nt = 0; nt < 3; ++nt)
                acc[mt][nt] = __builtin_amdgcn_mfma_f32_16x16x32_bf16(afr, cur[nt], acc[mt][nt], 0, 0, 0);
        }
    }

    const float qscale = 0.0625f * 1.44269504f;
    #pragma unroll
    for (int mt = 0; mt < 4; ++mt) {
        const int64_t g = row0 + mt * 16 + q16 * 4;
        #pragma unroll
        for (int nt = 0; nt < 3; ++nt) {
            const int ntb = n0 + nt * 16;             // wave-uniform
            const int n = ntb + l16;
            if (ntb < 64) {
                #pragma unroll
                for (int r = 0; r < 4; ++r)
                    Qb[(g + r) * 64 + n] = f2bf(acc[mt][nt][r] * qscale);
            } else if (ntb < 128) {
                #pragma unroll
                for (int r = 0; r < 4; ++r)
                    Kb[(g + r) * 64 + (n - 64)] = f2bf(acc[mt][nt][r]);
            } else {
                const int d = n - 128;
                const int ib = (int)(g >> 7);
                const int h = (int)(g & 127);
                *(ushort4*)&Vtb[((int64_t)(ib * 64 + d)) * 128 + h] =
                    make_ushort4(f2bf(acc[mt][nt][0]), f2bf(acc[mt][nt][1]),
                                 f2bf(acc[mt][nt][2]), f2bf(acc[mt][nt][3]));
            }
        }
    }
}

// ---------------- attention: async dbuf + unnormalized-P chunk pipeline ----
// (unchanged from Round 8)
#define PT_STRIDE 40    // 32 + 8 pad (80 B rows, 16B-aligned b128 reads)
__global__ __launch_bounds__(256, 2) void attn_mfma(
    const ushort* __restrict__ Qb, const ushort* __restrict__ Kb,
    const ushort* __restrict__ Vtb, float* __restrict__ out)
{
    __shared__ ushort Ks[2][8192];            // 2 x 16 KB, frag-linear
    __shared__ ushort Vt[2][8192];            // 2 x 16 KB, frag-linear
    __shared__ ushort Ps[4][2][16 * PT_STRIDE];  // 10,240 B

    const int t = threadIdx.x;
    const int blk = blockIdx.x;
    const int b  = ((blk & 7) << 3) | ((blk >> 3) & 7);   // XCD-major b
    const int j  = blk >> 6;
    const int jb = j * 64 + b;

    const int w = t >> 6, lane = t & 63;
    const int q16 = lane >> 4, l16 = lane & 15;

    int koff[4], voff[4], ldsoff[4];
    #pragma unroll
    for (int u = 0; u < 4; ++u) {
        const int fi = w * 4 + u;
        koff[u] = ((fi & 7) * 16 + l16) * 64 + (fi >> 3) * 32 + q16 * 8;
        voff[u] = ((fi & 3) * 16 + l16) * 128 + (fi >> 2) * 32 + q16 * 8;
        ldsoff[u] = fi * 512;   // ushorts
    }

    const int prow = jb * H_DIM + w * 16 + l16;
    short8 qa[2][2];
    #pragma unroll
    for (int hh = 0; hh < 2; ++hh)
        #pragma unroll
        for (int ks = 0; ks < 2; ++ks)
            qa[hh][ks] = *(const short8*)&Qb[(prow + hh * 64) * 64 + ks * 32 + q16 * 8];

    floatx4 of[2][4];
    #pragma unroll
    for (int hh = 0; hh < 2; ++hh)
        #pragma unroll
        for (int mt = 0; mt < 4; ++mt) of[hh][mt] = (floatx4){0.f, 0.f, 0.f, 0.f};

    {
        const ushort* kg = Kb + ((int64_t)b << 13);
        const ushort* vg = Vtb + ((int64_t)b << 13);
        #pragma unroll
        for (int u = 0; u < 4; ++u) {
            const int lo = __builtin_amdgcn_readfirstlane(ldsoff[u]);
            async_ld16(kg + koff[u], &Ks[0][lo]);
            async_ld16(vg + voff[u], &Vt[0][lo]);
        }
    }

    for (int i = 0; i < N_SEQ; ++i) {
        const int buf = i & 1;
        __syncthreads();   // drains stage(i); protects buf^1's prior readers

        if (i < N_SEQ - 1) {   // async stage of tile i+1
            const ushort* kg = Kb + ((int64_t)((i + 1) * B_DIM + b) << 13);
            const ushort* vg = Vtb + ((int64_t)((i + 1) * B_DIM + b) << 13);
            #pragma unroll
            for (int u = 0; u < 4; ++u) {
                const int lo = __builtin_amdgcn_readfirstlane(ldsoff[u]);
                async_ld16(kg + koff[u], &Ks[buf ^ 1][lo]);
                async_ld16(vg + voff[u], &Vt[buf ^ 1][lo]);
            }
        }

        float l[2] = {0.f, 0.f};
        floatx4 pv[2][4];
        #pragma unroll
        for (int hh = 0; hh < 2; ++hh)
            #pragma unroll
            for (int mt = 0; mt < 4; ++mt) pv[hh][mt] = (floatx4){0.f, 0.f, 0.f, 0.f};

        #pragma unroll
        for (int kq = 0; kq < 4; ++kq) {
            floatx4 sc[2][2];
            #pragma unroll
            for (int hh = 0; hh < 2; ++hh)
                #pragma unroll
                for (int tt = 0; tt < 2; ++tt) sc[hh][tt] = (floatx4){0.f, 0.f, 0.f, 0.f};
            #pragma unroll
            for (int ks = 0; ks < 2; ++ks)
                #pragma unroll
                for (int tt = 0; tt < 2; ++tt) {
                    const short8 ak = *(const short8*)&Ks[buf][(ks * 8 + kq * 2 + tt) * 512 + lane * 8];
                    sc[0][tt] = __builtin_amdgcn_mfma_f32_16x16x32_bf16(ak, qa[0][ks], sc[0][tt], 0, 0, 0);
                    sc[1][tt] = __builtin_amdgcn_mfma_f32_16x16x32_bf16(ak, qa[1][ks], sc[1][tt], 0, 0, 0);
                }

            #pragma unroll
            for (int hh = 0; hh < 2; ++hh)
                #pragma unroll
                for (int tt = 0; tt < 2; ++tt) {
                    const float e0 = __builtin_amdgcn_exp2f(sc[hh][tt][0]);
                    const float e1 = __builtin_amdgcn_exp2f(sc[hh][tt][1]);
                    const float e2 = __builtin_amdgcn_exp2f(sc[hh][tt][2]);
                    const float e3 = __builtin_amdgcn_exp2f(sc[hh][tt][3]);
                    l[hh] += (e0 + e1) + (e2 + e3);
                    *(ushort4*)&Ps[w][hh][l16 * PT_STRIDE + tt * 16 + q16 * 4] =
                        make_ushort4(f2bf(e0), f2bf(e1), f2bf(e2), f2bf(e3));
                }

            const short8 bp0 = *(const short8*)&Ps[w][0][l16 * PT_STRIDE + q16 * 8];
            const short8 bp1 = *(const short8*)&Ps[w][1][l16 * PT_STRIDE + q16 * 8];
            #pragma unroll
            for (int mt = 0; mt < 4; ++mt) {
                const short8 av = *(const short8*)&Vt[buf][(kq * 4 + mt) * 512 + lane * 8];
                pv[0][mt] = __builtin_amdgcn_mfma_f32_16x16x32_bf16(av, bp0, pv[0][mt], 0, 0, 0);
                pv[1][mt] = __builtin_amdgcn_mfma_f32_16x16x32_bf16(av, bp1, pv[1][mt], 0, 0, 0);
            }
        }

        #pragma unroll
        for (int hh = 0; hh < 2; ++hh) {
            float lt = l[hh];
            lt += __shfl_xor(lt, 16);
            lt += __shfl_xor(lt, 32);
            const float inv = __builtin_amdgcn_rcpf(lt);
            #pragma unroll
            for (int mt = 0; mt < 4; ++mt)
                #pragma unroll
                for (int r = 0; r < 4; ++r)
                    of[hh][mt][r] = fmaf(inv, pv[hh][mt][r], of[hh][mt][r]);
        }
    }

    #pragma unroll
    for (int hh = 0; hh < 2; ++hh)
        #pragma unroll
        for (int mt = 0; mt < 4; ++mt)
            *(float4*)&out[(int64_t)(prow + hh * 64) * HS + mt * 16 + q16 * 4] =
                make_float4(of[hh][mt][0], of[hh][mt][1], of[hh][mt][2], of[hh][mt][3]);
}

extern "C" void kernel_launch(void* const* d_in, const int* in_sizes, int n_in,
                              void* d_out, int out_size, void* d_ws, size_t ws_size,
                              hipStream_t stream)
{
    const float* x  = (const float*)d_in[0];
    const float* Wq = (const float*)d_in[1];
    const float* Wk = (const float*)d_in[2];
    const float* Wv = (const float*)d_in[3];
    float* out = (float*)d_out;

    const size_t qkv = (size_t)N_SEQ * B_DIM * H_DIM * HS;   // 4,194,304 elems
    ushort* Qb  = (ushort*)d_ws;
    ushort* Kb  = Qb + qkv;
    ushort* Vtb = Kb + qkv;
    ushort* Wtb = Vtb + qkv;                                 // 192*256 elems

    prep_w<<<192, 256, 0, stream>>>(Wq, Wk, Wv, Wtb);
    proj_mfma<<<(N_SEQ * B_DIM * H_DIM) / 64, 256, 0, stream>>>(x, Wtb, Qb, Kb, Vtb);
    attn_mfma<<<N_SEQ * B_DIM, 256, 0, stream>>>(Qb, Kb, Vtb, out);
}